// Round 8
// baseline (306.738 us; speedup 1.0000x reference)
//
#include <hip/hip_runtime.h>
#include <cstddef>

#define N_NODES 65536
#define NPER    1024
#define NGRAPH  64
#define HID     64
#define IN_F    128
#define KCLUS   16
#define NCLS    10
#define NCAP    64      // per-node neighbor capacity (deg ~ Poisson(16); overflow prob ~1e-20)
#define PLANE   (N_NODES * 4)   // ushort stride between quad-planes in transposed-packed es
#define HSTRIDE 12      // node-major LDS row stride (48 B, 16B-aligned)
#define LIN_BLOCKS 512  // N_NODES/128 tiles for the linear part of front_kernel

// ================================================================ GEMM tile core (verified round-0/3)
template <int K>
__device__ __forceinline__ void gemm_tile(const float* __restrict__ X,
                                          const float* __restrict__ W,
                                          float* __restrict__ Y,
                                          float (*xs)[68], float (*ws)[68],
                                          int block, int t) {
    const size_t row0 = (size_t)block * 128;
    const int rbase = t >> 3;   // 0..31
    const int cbase = t & 7;    // 0..7
    float acc[4][8] = {};

    for (int kc = 0; kc < K; kc += 64) {
        __syncthreads();
        for (int i = t; i < 128 * 16; i += 256) {   // X tile: 128 rows x 16 float4
            int row = i >> 4, k4 = (i & 15) << 2;
            *(float4*)&xs[row][k4] = *(const float4*)(X + (row0 + row) * K + kc + k4);
        }
        for (int i = t; i < 64 * 16; i += 256) {    // W tile: 64 rows x 16 float4
            int col = i >> 4, k4 = (i & 15) << 2;
            *(float4*)&ws[col][k4] = *(const float4*)(W + col * K + kc + k4);
        }
        __syncthreads();

#pragma unroll 4
        for (int k4 = 0; k4 < 64; k4 += 4) {
            float4 xr[4], wr[8];
#pragma unroll
            for (int rr = 0; rr < 4; ++rr) xr[rr] = *(const float4*)&xs[rbase + 32 * rr][k4];
#pragma unroll
            for (int cc = 0; cc < 8; ++cc) wr[cc] = *(const float4*)&ws[cbase + 8 * cc][k4];
#pragma unroll
            for (int rr = 0; rr < 4; ++rr)
#pragma unroll
                for (int cc = 0; cc < 8; ++cc) {
                    acc[rr][cc] = fmaf(xr[rr].x, wr[cc].x, acc[rr][cc]);
                    acc[rr][cc] = fmaf(xr[rr].y, wr[cc].y, acc[rr][cc]);
                    acc[rr][cc] = fmaf(xr[rr].z, wr[cc].z, acc[rr][cc]);
                    acc[rr][cc] = fmaf(xr[rr].w, wr[cc].w, acc[rr][cc]);
                }
        }
    }

#pragma unroll
    for (int rr = 0; rr < 4; ++rr)
#pragma unroll
        for (int cc = 0; cc < 8; ++cc)
            Y[(row0 + rbase + 32 * rr) * HID + cbase + 8 * cc] = acc[rr][cc];
}

// ---------------------------------------------------------------- front: linear1 (blocks 0..511) || single-pass edge build (blocks 512..)
// Build writes TRANSPOSED-PACKED per-node lists: entry p of node n lives at
// es[(p>>2)*PLANE + n*4 + (p&3)]. Agg's wave (64 consecutive nodes) then reads
// one uint2 per lane = contiguous 512 B per quad-step. Same-quad halfwords may
// be written from different XCDs; byte-granular writeback merge was empirically
// verified by round 6 (identical pattern, passed).
__global__ __launch_bounds__(256) void front_kernel(const float* __restrict__ X,
                                                    const float* __restrict__ W,
                                                    float* __restrict__ Y,
                                                    const int* __restrict__ src,
                                                    const int* __restrict__ dst,
                                                    int* __restrict__ deg,
                                                    unsigned short* __restrict__ es, int E) {
    __shared__ float xs[128][68];
    __shared__ float ws[64][68];
    const int t = threadIdx.x;

    if (blockIdx.x >= LIN_BLOCKS) {
        const int e0 = (blockIdx.x - LIN_BLOCKS) * 1024;
#pragma unroll
        for (int i = 0; i < 4; ++i) {
            int idx = e0 + i * 256 + t;
            if (idx < E) {
                int d = dst[idx], s = src[idx];
                int pos = atomicAdd(&deg[d], 1);
                if (pos < NCAP)
                    es[(size_t)(pos >> 2) * PLANE + (size_t)d * 4 + (pos & 3)] =
                        (unsigned short)(s & 1023);
            }
        }
        return;
    }

    gemm_tile<IN_F>(X, W, Y, xs, ws, blockIdx.x, t);
}

// ---------------------------------------------------------------- dense linear (conv2): Y = X @ W^T (verified, unchanged)
template <int K>
__global__ __launch_bounds__(256) void linear_kernel(const float* __restrict__ X,
                                                     const float* __restrict__ W,
                                                     float* __restrict__ Y) {
    __shared__ float xs[128][68];
    __shared__ float ws[64][68];
    gemm_tile<K>(X, W, Y, xs, ws, blockIdx.x, threadIdx.x);
}

// ---------------------------------------------------------------- pull aggregation (verified r6 core; transposed-packed es reads)
// Per quad-step the wave's 64 lanes read 64 consecutive nodes' uint2 -> fully
// coalesced. Tail (deg&3) uses the same quad load but only indexes the valid
// halfwords (stale halfwords are garbage and never dereferenced).
__global__ __launch_bounds__(512) void agg_kernel(const float* __restrict__ h,
                                                  const unsigned short* __restrict__ es,
                                                  const int* __restrict__ deg,
                                                  const float* __restrict__ bias,
                                                  float* __restrict__ outp) {
    __shared__ float Hs[NPER * HSTRIDE];
    __shared__ float dl[NPER];
    const int g = blockIdx.x & 63;          // same-XCD grouping (%8 invariant)
    const int f0 = (blockIdx.x >> 6) * 8;
    const int t = threadIdx.x;
    const int base = g * NPER;

    for (int r = t; r < NPER; r += 512) {
        const float* hp = h + (size_t)(base + r) * HID + f0;
        float4 a = *(const float4*)hp;
        float4 b = *(const float4*)(hp + 4);
        float dv = rsqrtf((float)deg[base + r] + 1.0f);
        dl[r] = dv;
        float* row = &Hs[r * HSTRIDE];
        *(float4*)row = make_float4(a.x * dv, a.y * dv, a.z * dv, a.w * dv);
        *(float4*)(row + 4) = make_float4(b.x * dv, b.y * dv, b.z * dv, b.w * dv);
    }
    float bb[8];
#pragma unroll
    for (int j = 0; j < 8; ++j) bb[j] = bias[f0 + j];
    __syncthreads();

    for (int ld = t; ld < NPER; ld += 512) {
        int dg = deg[base + ld];
        dg = dg < NCAP ? dg : NCAP;         // matches build-side drop (never hit in practice)
        const float* srow = &Hs[ld * HSTRIDE];
        float4 acc0 = *(const float4*)srow;         // self-loop: h*dv, final *dv -> h*dv^2
        float4 acc1 = *(const float4*)(srow + 4);
        float4 bcc0 = make_float4(0.f, 0.f, 0.f, 0.f);
        float4 bcc1 = make_float4(0.f, 0.f, 0.f, 0.f);

        const unsigned short* ep = es + (size_t)(base + ld) * 4;
        const int nq = dg >> 2, rem = dg & 3;
        for (int q = 0; q < nq; ++q) {
            uint2 w4 = *(const uint2*)(ep + (size_t)q * PLANE);
            const float* r0 = &Hs[(int)(w4.x & 0xFFFFu) * HSTRIDE];
            const float* r1 = &Hs[(int)(w4.x >> 16) * HSTRIDE];
            const float* r2 = &Hs[(int)(w4.y & 0xFFFFu) * HSTRIDE];
            const float* r3 = &Hs[(int)(w4.y >> 16) * HSTRIDE];
            float4 a0 = *(const float4*)r0, a1 = *(const float4*)(r0 + 4);
            float4 b0 = *(const float4*)r1, b1 = *(const float4*)(r1 + 4);
            float4 c0v = *(const float4*)r2, c1v = *(const float4*)(r2 + 4);
            float4 d0 = *(const float4*)r3, d1 = *(const float4*)(r3 + 4);
            acc0.x += a0.x; acc0.y += a0.y; acc0.z += a0.z; acc0.w += a0.w;
            acc1.x += a1.x; acc1.y += a1.y; acc1.z += a1.z; acc1.w += a1.w;
            bcc0.x += b0.x; bcc0.y += b0.y; bcc0.z += b0.z; bcc0.w += b0.w;
            bcc1.x += b1.x; bcc1.y += b1.y; bcc1.z += b1.z; bcc1.w += b1.w;
            acc0.x += c0v.x; acc0.y += c0v.y; acc0.z += c0v.z; acc0.w += c0v.w;
            acc1.x += c1v.x; acc1.y += c1v.y; acc1.z += c1v.z; acc1.w += c1v.w;
            bcc0.x += d0.x; bcc0.y += d0.y; bcc0.z += d0.z; bcc0.w += d0.w;
            bcc1.x += d1.x; bcc1.y += d1.y; bcc1.z += d1.z; bcc1.w += d1.w;
        }
        if (rem) {                          // tail quad: only valid halfwords indexed
            uint2 w4 = *(const uint2*)(ep + (size_t)nq * PLANE);
            unsigned sx0 = w4.x & 0xFFFFu, sx1 = w4.x >> 16, sx2 = w4.y & 0xFFFFu;
            {
                const float* rr = &Hs[(int)sx0 * HSTRIDE];
                float4 e0 = *(const float4*)rr, e1 = *(const float4*)(rr + 4);
                acc0.x += e0.x; acc0.y += e0.y; acc0.z += e0.z; acc0.w += e0.w;
                acc1.x += e1.x; acc1.y += e1.y; acc1.z += e1.z; acc1.w += e1.w;
            }
            if (rem > 1) {
                const float* rr = &Hs[(int)sx1 * HSTRIDE];
                float4 e0 = *(const float4*)rr, e1 = *(const float4*)(rr + 4);
                bcc0.x += e0.x; bcc0.y += e0.y; bcc0.z += e0.z; bcc0.w += e0.w;
                bcc1.x += e1.x; bcc1.y += e1.y; bcc1.z += e1.z; bcc1.w += e1.w;
            }
            if (rem > 2) {
                const float* rr = &Hs[(int)sx2 * HSTRIDE];
                float4 e0 = *(const float4*)rr, e1 = *(const float4*)(rr + 4);
                acc0.x += e0.x; acc0.y += e0.y; acc0.z += e0.z; acc0.w += e0.w;
                acc1.x += e1.x; acc1.y += e1.y; acc1.z += e1.z; acc1.w += e1.w;
            }
        }
        acc0.x += bcc0.x; acc0.y += bcc0.y; acc0.z += bcc0.z; acc0.w += bcc0.w;
        acc1.x += bcc1.x; acc1.y += bcc1.y; acc1.z += bcc1.z; acc1.w += bcc1.w;

        const float dv = dl[ld];
        float4 o0, o1;
        o0.x = fmaxf(fmaf(acc0.x, dv, bb[0]), 0.f);
        o0.y = fmaxf(fmaf(acc0.y, dv, bb[1]), 0.f);
        o0.z = fmaxf(fmaf(acc0.z, dv, bb[2]), 0.f);
        o0.w = fmaxf(fmaf(acc0.w, dv, bb[3]), 0.f);
        o1.x = fmaxf(fmaf(acc1.x, dv, bb[4]), 0.f);
        o1.y = fmaxf(fmaf(acc1.y, dv, bb[5]), 0.f);
        o1.z = fmaxf(fmaf(acc1.z, dv, bb[6]), 0.f);
        o1.w = fmaxf(fmaf(acc1.w, dv, bb[7]), 0.f);
        float* op = outp + (size_t)(base + ld) * HID + f0;
        *(float4*)op = o0;
        *(float4*)(op + 4) = o1;
    }
}

// ---------------------------------------------------------------- fused DMoN pool (pool1+pool2 in one 64-block kernel)
// One block per graph, 1024 threads. Loops 8 chunks of 128 rows: stage chunk,
// softmax assignment (pool1's verified per-row math, t<128), accumulate
// S^T X into registers (t<256 owns (h, k-quad), acc[4] across chunks).
// Epilogue: selu -> mean over clusters -> classifier (pool2's verified math).
// Removes one dispatch and the xpart HBM round trip.
__global__ __launch_bounds__(1024) void megapool_kernel(const float* __restrict__ h,
                                                        const float* __restrict__ Wp,
                                                        const float* __restrict__ bp,
                                                        const float* __restrict__ Wl,
                                                        const float* __restrict__ bl,
                                                        float* __restrict__ out) {
    __shared__ float xs[128][HID + 1];
    __shared__ float ss[128][KCLUS + 1];
    __shared__ float wp[KCLUS][HID];
    __shared__ float bps[KCLUS];
    __shared__ float xp[KCLUS][HID + 1];
    __shared__ float outm[HID];
    const int g = blockIdx.x;
    const int t = threadIdx.x;
    const int hcol = t & 63;
    const int k0 = ((t >> 6) & 3) * 4;

    for (int i = t; i < KCLUS * HID; i += 1024) wp[i >> 6][i & 63] = Wp[i];
    if (t < KCLUS) bps[t] = bp[t];

    float acc4[4] = {0.f, 0.f, 0.f, 0.f};

    for (int c = 0; c < 8; ++c) {
        __syncthreads();                    // protect xs/ss from previous phase-B readers
        const float* hb = h + ((size_t)g * NPER + c * 128) * HID;
        for (int i = t; i < 128 * HID / 4; i += 1024) {
            float4 v = ((const float4*)hb)[i];
            int row = i >> 4, col = (i & 15) * 4;
            xs[row][col] = v.x; xs[row][col + 1] = v.y;
            xs[row][col + 2] = v.z; xs[row][col + 3] = v.w;
        }
        __syncthreads();

        if (t < 128) {                      // pool1's verified softmax-assignment math
            float lg[KCLUS];
            float mx = -1e30f;
#pragma unroll
            for (int k = 0; k < KCLUS; ++k) {
                float a = bps[k];
#pragma unroll 8
                for (int hh = 0; hh < HID; ++hh) a = fmaf(xs[t][hh], wp[k][hh], a);
                lg[k] = a;
                mx = fmaxf(mx, a);
            }
            float sum = 0.f;
#pragma unroll
            for (int k = 0; k < KCLUS; ++k) {
                lg[k] = __expf(lg[k] - mx);
                sum += lg[k];
            }
            float inv = 1.0f / sum;
#pragma unroll
            for (int k = 0; k < KCLUS; ++k) ss[t][k] = lg[k] * inv;
        }
        __syncthreads();

        if (t < 256) {                      // pool1's verified accumulate, regs across chunks
#pragma unroll 8
            for (int n = 0; n < 128; ++n) {
                float xv = xs[n][hcol];
                acc4[0] = fmaf(ss[n][k0 + 0], xv, acc4[0]);
                acc4[1] = fmaf(ss[n][k0 + 1], xv, acc4[1]);
                acc4[2] = fmaf(ss[n][k0 + 2], xv, acc4[2]);
                acc4[3] = fmaf(ss[n][k0 + 3], xv, acc4[3]);
            }
        }
    }

    // ---- epilogue: selu, mean over clusters, classifier (pool2's math) ----
    if (t < 256) {
        const float sc = 1.0507009873554805f, al = 1.6732632423543772f;
#pragma unroll
        for (int j = 0; j < 4; ++j) {
            float v = acc4[j];
            xp[k0 + j][hcol] = v > 0.f ? sc * v : sc * al * (__expf(v) - 1.f);
        }
    }
    __syncthreads();

    if (t < HID) {
        float m = 0.f;
#pragma unroll
        for (int k = 0; k < KCLUS; ++k) m += xp[k][t];
        outm[t] = m * (1.0f / KCLUS);
    }
    __syncthreads();

    if (t < NCLS) {
        float acc = bl[t];
#pragma unroll 8
        for (int hh = 0; hh < HID; ++hh) acc = fmaf(outm[hh], Wl[t * HID + hh], acc);
        out[g * NCLS + t] = acc;
    }
}

// ---------------------------------------------------------------- launch
extern "C" void kernel_launch(void* const* d_in, const int* in_sizes, int n_in,
                              void* d_out, int out_size, void* d_ws, size_t ws_size,
                              hipStream_t stream) {
    const float* x  = (const float*)d_in[0];
    const int* eidx = (const int*)d_in[1];
    const float* W1 = (const float*)d_in[3];
    const float* b1 = (const float*)d_in[4];
    const float* W2 = (const float*)d_in[5];
    const float* b2 = (const float*)d_in[6];
    const float* Wp = (const float*)d_in[7];
    const float* bp = (const float*)d_in[8];
    const float* Wl = (const float*)d_in[9];
    const float* bl = (const float*)d_in[10];
    float* out = (float*)d_out;

    const int E = in_sizes[1] / 2;
    const int* src = eidx;
    const int* dst = eidx + E;

    // workspace layout: deg | es (transposed-packed) | A | Bf
    char* w = (char*)d_ws;
    int*            deg = (int*)w;            w += (size_t)N_NODES * 4;
    unsigned short* es  = (unsigned short*)w; w += (size_t)N_NODES * NCAP * 2;
    float*          A   = (float*)w;          w += (size_t)N_NODES * HID * 4;
    float*          Bf  = (float*)w;          w += (size_t)N_NODES * HID * 4;

    hipMemsetAsync(deg, 0, (size_t)N_NODES * 4, stream);

    // linear1 || single-pass transposed edge-list build (independent) in one dispatch
    const int nbuild = (E + 1023) / 1024;
    front_kernel<<<LIN_BLOCKS + nbuild, 256, 0, stream>>>(x, W1, A, src, dst, deg, es, E);

    // conv1 aggregation: A -> Bf  (bias1 + relu fused)
    agg_kernel<<<NGRAPH * 8, 512, 0, stream>>>(A, es, deg, b1, Bf);

    // conv2: Bf -> A (GEMM), then aggregation A -> Bf (bias2 + relu fused)
    linear_kernel<HID><<<N_NODES / 128, 256, 0, stream>>>(Bf, W2, A);
    agg_kernel<<<NGRAPH * 8, 512, 0, stream>>>(A, es, deg, b2, Bf);

    // DMoN pooling + classifier, single dispatch
    megapool_kernel<<<NGRAPH, 1024, 0, stream>>>(Bf, Wp, bp, Wl, bl, out);
}

// Round 9
// 216.251 us; speedup vs baseline: 1.4184x; 1.4184x over previous
//
#include <hip/hip_runtime.h>
#include <cstddef>

#define N_NODES 65536
#define NPER    1024
#define NGRAPH  64
#define HID     64
#define IN_F    128
#define KCLUS   16
#define NCLS    10
#define ECAP    20480   // per-graph capacity incl. 4-alignment padding
#define HSTRIDE 12      // node-major LDS row stride (48 B, 16B-aligned)
#define ZROW    NPER    // index of the all-zero LDS row used by padding entries
#define LIN_BLOCKS 1024 // N_NODES/64 tiles for the linear part of front_kernel

// ================================================================ 64-row GEMM tile (front)
// 64 rows x 64 cols per block, 256 threads, 2x8 per thread. Halved LDS
// (34816 B -> 4 blocks/CU vs 3) so front's 1536 blocks fit in ~1.5 scheduling
// rounds instead of 2 full rounds of double-size tiles. Same conflict-free
// row-major bank pattern as the verified 128-row tile.
template <int K>
__device__ __forceinline__ void gemm_tile64(const float* __restrict__ X,
                                            const float* __restrict__ W,
                                            float* __restrict__ Y,
                                            float (*xs)[68], float (*ws)[68],
                                            int block, int t) {
    const size_t row0 = (size_t)block * 64;
    const int rbase = t >> 3;   // 0..31, rows {rbase, rbase+32}
    const int cbase = t & 7;    // 0..7
    float acc[2][8] = {};

    for (int kc = 0; kc < K; kc += 64) {
        __syncthreads();
        for (int i = t; i < 64 * 16; i += 256) {    // X tile: 64 rows x 16 float4
            int row = i >> 4, k4 = (i & 15) << 2;
            *(float4*)&xs[row][k4] = *(const float4*)(X + (row0 + row) * K + kc + k4);
        }
        for (int i = t; i < 64 * 16; i += 256) {    // W tile: 64 rows x 16 float4
            int col = i >> 4, k4 = (i & 15) << 2;
            *(float4*)&ws[col][k4] = *(const float4*)(W + col * K + kc + k4);
        }
        __syncthreads();

#pragma unroll 4
        for (int k4 = 0; k4 < 64; k4 += 4) {
            float4 xr[2], wr[8];
#pragma unroll
            for (int rr = 0; rr < 2; ++rr) xr[rr] = *(const float4*)&xs[rbase + 32 * rr][k4];
#pragma unroll
            for (int cc = 0; cc < 8; ++cc) wr[cc] = *(const float4*)&ws[cbase + 8 * cc][k4];
#pragma unroll
            for (int rr = 0; rr < 2; ++rr)
#pragma unroll
                for (int cc = 0; cc < 8; ++cc) {
                    acc[rr][cc] = fmaf(xr[rr].x, wr[cc].x, acc[rr][cc]);
                    acc[rr][cc] = fmaf(xr[rr].y, wr[cc].y, acc[rr][cc]);
                    acc[rr][cc] = fmaf(xr[rr].z, wr[cc].z, acc[rr][cc]);
                    acc[rr][cc] = fmaf(xr[rr].w, wr[cc].w, acc[rr][cc]);
                }
        }
    }

#pragma unroll
    for (int rr = 0; rr < 2; ++rr)
#pragma unroll
        for (int cc = 0; cc < 8; ++cc)
            Y[(row0 + rbase + 32 * rr) * HID + cbase + 8 * cc] = acc[rr][cc];
}

// ================================================================ 128-row GEMM tile (lin2, verified round-0/3, unchanged)
template <int K>
__device__ __forceinline__ void gemm_tile(const float* __restrict__ X,
                                          const float* __restrict__ W,
                                          float* __restrict__ Y,
                                          float (*xs)[68], float (*ws)[68],
                                          int block, int t) {
    const size_t row0 = (size_t)block * 128;
    const int rbase = t >> 3;   // 0..31
    const int cbase = t & 7;    // 0..7
    float acc[4][8] = {};

    for (int kc = 0; kc < K; kc += 64) {
        __syncthreads();
        for (int i = t; i < 128 * 16; i += 256) {
            int row = i >> 4, k4 = (i & 15) << 2;
            *(float4*)&xs[row][k4] = *(const float4*)(X + (row0 + row) * K + kc + k4);
        }
        for (int i = t; i < 64 * 16; i += 256) {
            int col = i >> 4, k4 = (i & 15) << 2;
            *(float4*)&ws[col][k4] = *(const float4*)(W + col * K + kc + k4);
        }
        __syncthreads();

#pragma unroll 4
        for (int k4 = 0; k4 < 64; k4 += 4) {
            float4 xr[4], wr[8];
#pragma unroll
            for (int rr = 0; rr < 4; ++rr) xr[rr] = *(const float4*)&xs[rbase + 32 * rr][k4];
#pragma unroll
            for (int cc = 0; cc < 8; ++cc) wr[cc] = *(const float4*)&ws[cbase + 8 * cc][k4];
#pragma unroll
            for (int rr = 0; rr < 4; ++rr)
#pragma unroll
                for (int cc = 0; cc < 8; ++cc) {
                    acc[rr][cc] = fmaf(xr[rr].x, wr[cc].x, acc[rr][cc]);
                    acc[rr][cc] = fmaf(xr[rr].y, wr[cc].y, acc[rr][cc]);
                    acc[rr][cc] = fmaf(xr[rr].z, wr[cc].z, acc[rr][cc]);
                    acc[rr][cc] = fmaf(xr[rr].w, wr[cc].w, acc[rr][cc]);
                }
        }
    }

#pragma unroll
    for (int rr = 0; rr < 4; ++rr)
#pragma unroll
        for (int cc = 0; cc < 8; ++cc)
            Y[(row0 + rbase + 32 * rr) * HID + cbase + 8 * cc] = acc[rr][cc];
}

// ---------------------------------------------------------------- front: linear1 (blocks 0..1023, 64-row tiles) || bucket (blocks 1024..)
// Bucket arm: verified r0 logic at 8 edges/thread (2048 edges/block).
__global__ __launch_bounds__(256) void front_kernel(const float* __restrict__ X,
                                                    const float* __restrict__ W,
                                                    float* __restrict__ Y,
                                                    const int* __restrict__ src,
                                                    const int* __restrict__ dst,
                                                    int* __restrict__ ecnt,
                                                    int* __restrict__ gedges, int E) {
    __shared__ float xs[64][68];
    __shared__ float ws[64][68];
    const int t = threadIdx.x;

    if (blockIdx.x >= LIN_BLOCKS) {
        // ---------------- bucket part (LDS aliased onto xs)
        int* hist = (int*)&xs[0][0];
        int* base_l = hist + NGRAPH;
        const int e0 = (blockIdx.x - LIN_BLOCKS) * 2048;
        if (t < NGRAPH) hist[t] = 0;
        __syncthreads();

        int gg[8], rr[8], pk[8];
#pragma unroll
        for (int i = 0; i < 8; ++i) {
            int idx = e0 + i * 256 + t;
            if (idx < E) {
                int d = dst[idx], s = src[idx];
                int g = d >> 10;
                gg[i] = g;
                pk[i] = ((d & 1023) << 10) | (s & 1023);
                rr[i] = atomicAdd(&hist[g], 1);
            } else gg[i] = -1;
        }
        __syncthreads();
        if (t < NGRAPH) base_l[t] = atomicAdd(&ecnt[t], hist[t]);
        __syncthreads();
#pragma unroll
        for (int i = 0; i < 8; ++i) {
            if (gg[i] >= 0) {
                int pos = base_l[gg[i]] + rr[i];
                if (pos < ECAP) gedges[gg[i] * ECAP + pos] = pk[i];
            }
        }
        return;
    }

    gemm_tile64<IN_F>(X, W, Y, xs, ws, blockIdx.x, t);
}

// ---------------------------------------------------------------- dense linear (conv2): Y = X @ W^T (verified, unchanged)
template <int K>
__global__ __launch_bounds__(256) void linear_kernel(const float* __restrict__ X,
                                                     const float* __restrict__ W,
                                                     float* __restrict__ Y) {
    __shared__ float xs[128][68];
    __shared__ float ws[64][68];
    gemm_tile<K>(X, W, Y, xs, ws, blockIdx.x, threadIdx.x);
}

// ---------------------------------------------------------------- distributed CSR build, dst-range partitioned (verified round-3, unchanged)
__global__ __launch_bounds__(1024) void scatter_kernel(const int* __restrict__ gedges,
                                                       const int* __restrict__ ecnt,
                                                       int* __restrict__ rp,
                                                       unsigned short* __restrict__ esorted,
                                                       float* __restrict__ dinv) {
    __shared__ int hist[NPER];
    __shared__ int wsum[16];
    const int g = blockIdx.x >> 3;
    const int sub = blockIdx.x & 7;          // owns dst rows [sub*128, sub*128+128)
    const int t = threadIdx.x;
    const int lane = t & 63, wid = t >> 6;
    const int ec = ecnt[g];
    const int* ge = gedges + (size_t)g * ECAP;

    hist[t] = 0;
    __syncthreads();
    for (int i = t; i < ec; i += 1024) atomicAdd(&hist[ge[i] >> 10], 1);
    __syncthreads();

    const int h0 = hist[t];
    const int pd = (h0 + 3) & ~3;   // padded degree
    int v = pd;
#pragma unroll
    for (int off = 1; off < 64; off <<= 1) {
        int x = __shfl_up(v, off, 64);
        if (lane >= off) v += x;
    }
    if (lane == 63) wsum[wid] = v;
    __syncthreads();
    if (wid == 0) {
        int wv = (lane < 16) ? wsum[lane] : 0;
#pragma unroll
        for (int off = 1; off < 16; off <<= 1) {
            int x = __shfl_up(wv, off, 64);
            if (lane >= off) wv += x;
        }
        if (lane < 16) wsum[lane] = wv;
    }
    __syncthreads();
    const int incl = v + (wid > 0 ? wsum[wid - 1] : 0);
    const int excl = incl - pd;

    if (sub == 0) {                          // one block per graph publishes rp/dinv
        rp[g * (NPER + 1) + t] = excl;
        if (t == NPER - 1) rp[g * (NPER + 1) + NPER] = incl;
        dinv[g * NPER + t] = rsqrtf((float)h0 + 1.0f);
    }
    __syncthreads();
    hist[t] = excl;                          // scatter cursor (row start)
    __syncthreads();

    unsigned short* es = esorted + (size_t)g * ECAP;

    // padding: thread t owns row t; gate to this block's row range
    if ((t >> 7) == sub)
        for (int q = excl + h0; q < excl + pd; ++q) es[q] = (unsigned short)ZROW;

    // scatter: only edges targeting this block's dst range, LDS cursors
    for (int i = t; i < ec; i += 1024) {
        int pk = ge[i];
        int d = pk >> 10;
        if ((d >> 7) == sub) {
            int pos = atomicAdd(&hist[d], 1);
            es[pos] = (unsigned short)(pk & 1023);
        }
    }
}

// ---------------------------------------------------------------- pull-based aggregation (verified round-0/3 core)
// Single change vs verified: dl[] LDS array removed (dinv reloaded from global
// in the epilogue; 4 KB/graph, L2-hot). LDS 53296 -> 49200 B => 3 blocks/CU
// instead of 2 (24 waves vs 16) for the latency-bound gather.
__global__ __launch_bounds__(512) void agg_kernel(const float* __restrict__ h,
                                                  const unsigned short* __restrict__ esorted,
                                                  const int* __restrict__ rp,
                                                  const float* __restrict__ dinv,
                                                  const float* __restrict__ bias,
                                                  float* __restrict__ outp) {
    __shared__ float Hs[(NPER + 1) * HSTRIDE];
    const int g = blockIdx.x & 63;          // same-XCD grouping (%8 invariant)
    const int f0 = (blockIdx.x >> 6) * 8;
    const int t = threadIdx.x;
    const int base = g * NPER;

    for (int r = t; r < NPER; r += 512) {
        const float* hp = h + (size_t)(base + r) * HID + f0;
        float4 a = *(const float4*)hp;
        float4 b = *(const float4*)(hp + 4);
        float dv = dinv[base + r];
        float* row = &Hs[r * HSTRIDE];
        *(float4*)row = make_float4(a.x * dv, a.y * dv, a.z * dv, a.w * dv);
        *(float4*)(row + 4) = make_float4(b.x * dv, b.y * dv, b.z * dv, b.w * dv);
    }
    if (t < HSTRIDE) Hs[ZROW * HSTRIDE + t] = 0.f;
    float bb[8];
#pragma unroll
    for (int j = 0; j < 8; ++j) bb[j] = bias[f0 + j];
    const unsigned short* es = esorted + (size_t)g * ECAP;
    const int* rpg = rp + g * (NPER + 1);
    __syncthreads();

    for (int ld = t; ld < NPER; ld += 512) {
        int p = rpg[ld];
        const int pe = rpg[ld + 1];
        const float* srow = &Hs[ld * HSTRIDE];
        float4 acc0 = *(const float4*)srow;
        float4 acc1 = *(const float4*)(srow + 4);
        float4 bcc0 = make_float4(0.f, 0.f, 0.f, 0.f);
        float4 bcc1 = make_float4(0.f, 0.f, 0.f, 0.f);

        for (; p < pe; p += 4) {
            uint2 w4 = *(const uint2*)(es + p);
            const float* r0 = &Hs[(int)(w4.x & 0xFFFFu) * HSTRIDE];
            const float* r1 = &Hs[(int)(w4.x >> 16) * HSTRIDE];
            const float* r2 = &Hs[(int)(w4.y & 0xFFFFu) * HSTRIDE];
            const float* r3 = &Hs[(int)(w4.y >> 16) * HSTRIDE];
            float4 a0 = *(const float4*)r0, a1 = *(const float4*)(r0 + 4);
            float4 b0 = *(const float4*)r1, b1 = *(const float4*)(r1 + 4);
            float4 c0v = *(const float4*)r2, c1v = *(const float4*)(r2 + 4);
            float4 d0 = *(const float4*)r3, d1 = *(const float4*)(r3 + 4);
            acc0.x += a0.x; acc0.y += a0.y; acc0.z += a0.z; acc0.w += a0.w;
            acc1.x += a1.x; acc1.y += a1.y; acc1.z += a1.z; acc1.w += a1.w;
            bcc0.x += b0.x; bcc0.y += b0.y; bcc0.z += b0.z; bcc0.w += b0.w;
            bcc1.x += b1.x; bcc1.y += b1.y; bcc1.z += b1.z; bcc1.w += b1.w;
            acc0.x += c0v.x; acc0.y += c0v.y; acc0.z += c0v.z; acc0.w += c0v.w;
            acc1.x += c1v.x; acc1.y += c1v.y; acc1.z += c1v.z; acc1.w += c1v.w;
            bcc0.x += d0.x; bcc0.y += d0.y; bcc0.z += d0.z; bcc0.w += d0.w;
            bcc1.x += d1.x; bcc1.y += d1.y; bcc1.z += d1.z; bcc1.w += d1.w;
        }
        acc0.x += bcc0.x; acc0.y += bcc0.y; acc0.z += bcc0.z; acc0.w += bcc0.w;
        acc1.x += bcc1.x; acc1.y += bcc1.y; acc1.z += bcc1.z; acc1.w += bcc1.w;

        const float dv = dinv[base + ld];
        float4 o0, o1;
        o0.x = fmaxf(fmaf(acc0.x, dv, bb[0]), 0.f);
        o0.y = fmaxf(fmaf(acc0.y, dv, bb[1]), 0.f);
        o0.z = fmaxf(fmaf(acc0.z, dv, bb[2]), 0.f);
        o0.w = fmaxf(fmaf(acc0.w, dv, bb[3]), 0.f);
        o1.x = fmaxf(fmaf(acc1.x, dv, bb[4]), 0.f);
        o1.y = fmaxf(fmaf(acc1.y, dv, bb[5]), 0.f);
        o1.z = fmaxf(fmaf(acc1.z, dv, bb[6]), 0.f);
        o1.w = fmaxf(fmaf(acc1.w, dv, bb[7]), 0.f);
        float* op = outp + (size_t)(base + ld) * HID + f0;
        *(float4*)op = o0;
        *(float4*)(op + 4) = o1;
    }
}

// ---------------------------------------------------------------- fused DMoN phase 1 (verified, unchanged)
__global__ __launch_bounds__(256) void pool1_kernel(const float* __restrict__ h,
                                                    const float* __restrict__ Wp,
                                                    const float* __restrict__ bp,
                                                    float* __restrict__ xpart) {
    __shared__ float xs[128][HID + 1];
    __shared__ float ss[128][KCLUS + 1];
    __shared__ float wp[KCLUS][HID];
    __shared__ float bps[KCLUS];
    const int g = blockIdx.x >> 3;
    const int c = blockIdx.x & 7;
    const int t = threadIdx.x;
    const float* hb = h + ((size_t)g * NPER + c * 128) * HID;

    for (int i = t; i < 128 * HID / 4; i += 256) {
        float4 v = ((const float4*)hb)[i];
        int row = i >> 4, col = (i & 15) * 4;
        xs[row][col] = v.x; xs[row][col + 1] = v.y; xs[row][col + 2] = v.z; xs[row][col + 3] = v.w;
    }
    for (int i = t; i < KCLUS * HID; i += 256) wp[i >> 6][i & 63] = Wp[i];
    if (t < KCLUS) bps[t] = bp[t];
    __syncthreads();

    if (t < 128) {
        float lg[KCLUS];
        float mx = -1e30f;
#pragma unroll
        for (int k = 0; k < KCLUS; ++k) {
            float a = bps[k];
#pragma unroll 8
            for (int hh = 0; hh < HID; ++hh) a = fmaf(xs[t][hh], wp[k][hh], a);
            lg[k] = a;
            mx = fmaxf(mx, a);
        }
        float sum = 0.f;
#pragma unroll
        for (int k = 0; k < KCLUS; ++k) {
            lg[k] = __expf(lg[k] - mx);
            sum += lg[k];
        }
        float inv = 1.0f / sum;
#pragma unroll
        for (int k = 0; k < KCLUS; ++k) ss[t][k] = lg[k] * inv;
    }
    __syncthreads();

    const int hcol = t & 63;
    const int k0 = (t >> 6) * 4;
    float a0 = 0.f, a1 = 0.f, a2 = 0.f, a3 = 0.f;
#pragma unroll 8
    for (int n = 0; n < 128; ++n) {
        float xv = xs[n][hcol];
        a0 = fmaf(ss[n][k0 + 0], xv, a0);
        a1 = fmaf(ss[n][k0 + 1], xv, a1);
        a2 = fmaf(ss[n][k0 + 2], xv, a2);
        a3 = fmaf(ss[n][k0 + 3], xv, a3);
    }
    float* xp = xpart + (((size_t)(g * 8 + c)) * KCLUS + k0) * HID + hcol;
    xp[0] = a0; xp[HID] = a1; xp[2 * HID] = a2; xp[3 * HID] = a3;
}

// ---------------------------------------------------------------- DMoN phase 2 (verified, unchanged)
__global__ __launch_bounds__(256) void pool2_kernel(const float* __restrict__ xpart,
                                                    const float* __restrict__ Wl,
                                                    const float* __restrict__ bl,
                                                    float* __restrict__ out) {
    __shared__ float xp[KCLUS][HID + 1];
    __shared__ float outm[HID];
    const int g = blockIdx.x;
    const int t = threadIdx.x;
    const int hcol = t & 63;
    const int k0 = (t >> 6) * 4;
    const float* base = xpart + (size_t)g * 8 * KCLUS * HID;

    float a[4] = {};
#pragma unroll
    for (int c = 0; c < 8; ++c)
#pragma unroll
        for (int j = 0; j < 4; ++j)
            a[j] += base[(c * KCLUS + k0 + j) * HID + hcol];

    const float sc = 1.0507009873554805f, al = 1.6732632423543772f;
#pragma unroll
    for (int j = 0; j < 4; ++j) {
        float v = a[j];
        xp[k0 + j][hcol] = v > 0.f ? sc * v : sc * al * (__expf(v) - 1.f);
    }
    __syncthreads();

    if (t < HID) {
        float m = 0.f;
#pragma unroll
        for (int k = 0; k < KCLUS; ++k) m += xp[k][t];
        outm[t] = m * (1.0f / KCLUS);
    }
    __syncthreads();

    if (t < NCLS) {
        float acc = bl[t];
#pragma unroll 8
        for (int hh = 0; hh < HID; ++hh) acc = fmaf(outm[hh], Wl[t * HID + hh], acc);
        out[g * NCLS + t] = acc;
    }
}

// ---------------------------------------------------------------- launch
extern "C" void kernel_launch(void* const* d_in, const int* in_sizes, int n_in,
                              void* d_out, int out_size, void* d_ws, size_t ws_size,
                              hipStream_t stream) {
    const float* x  = (const float*)d_in[0];
    const int* eidx = (const int*)d_in[1];
    const float* W1 = (const float*)d_in[3];
    const float* b1 = (const float*)d_in[4];
    const float* W2 = (const float*)d_in[5];
    const float* b2 = (const float*)d_in[6];
    const float* Wp = (const float*)d_in[7];
    const float* bp = (const float*)d_in[8];
    const float* Wl = (const float*)d_in[9];
    const float* bl = (const float*)d_in[10];
    float* out = (float*)d_out;

    const int E = in_sizes[1] / 2;
    const int* src = eidx;
    const int* dst = eidx + E;

    // workspace layout: ecnt | gedges | esorted | rp | dinv | A | Bf | xpart
    char* w = (char*)d_ws;
    int*            ecnt    = (int*)w;            w += 256;
    int*            gedges  = (int*)w;            w += (size_t)NGRAPH * ECAP * 4;
    unsigned short* esorted = (unsigned short*)w; w += (size_t)NGRAPH * ECAP * 2;
    int*            rp      = (int*)w;            w += (size_t)NGRAPH * (NPER + 1) * 4;
    float*          dinv    = (float*)w;          w += (size_t)N_NODES * 4;
    float*          A       = (float*)w;          w += (size_t)N_NODES * HID * 4;
    float*          Bf      = (float*)w;          w += (size_t)N_NODES * HID * 4;
    float*          xpart   = (float*)w;          w += (size_t)NGRAPH * 8 * KCLUS * HID * 4;

    hipMemsetAsync(ecnt, 0, 256, stream);

    // linear1 (64-row tiles, 4 blocks/CU) || bucket (8 edges/thread) in one dispatch
    const int nbucket = (E + 2047) / 2048;
    front_kernel<<<LIN_BLOCKS + nbucket, 256, 0, stream>>>(x, W1, A, src, dst, ecnt, gedges, E);

    // distributed CSR build (verified r3)
    scatter_kernel<<<NGRAPH * 8, 1024, 0, stream>>>(gedges, ecnt, rp, esorted, dinv);

    // conv1 aggregation: A -> Bf
    agg_kernel<<<NGRAPH * 8, 512, 0, stream>>>(A, esorted, rp, dinv, b1, Bf);

    // conv2: Bf -> A -> Bf
    linear_kernel<HID><<<N_NODES / 128, 256, 0, stream>>>(Bf, W2, A);
    agg_kernel<<<NGRAPH * 8, 512, 0, stream>>>(A, esorted, rp, dinv, b2, Bf);

    // DMoN pooling + classifier
    pool1_kernel<<<NGRAPH * 8, 256, 0, stream>>>(Bf, Wp, bp, xpart);
    pool2_kernel<<<NGRAPH, 256, 0, stream>>>(xpart, Wl, bl, out);
}